// Round 6
// baseline (365.505 us; speedup 1.0000x reference)
//
#include <hip/hip_runtime.h>
#include <hip/hip_bf16.h>

// GATNet: 2x GATConv + 2-layer MLP.
// R5 -> R6: LINEARITY TRICK for conv1. Since h1 = x@W1 is linear,
//   sum_e alpha_e h1[src] = (sum_e alpha_e x[src]) @ W1.
// So agg1 gathers x rows (256B, 12.8MB array) instead of h1 rows (512B,
// 25.6MB) -> halves the irreducible per-XCD L2-miss traffic (R5 showed
// FETCH ~= 8 XCDs x array size; random graph = no locality to mine).
// W1 applied AFTER aggregation as two (N,128)@(128,128) MFMA GEMMs (+elu).
// Alphas computed directly from x via va = W1_h @ a1_h (exact same math).
// h1b buffer and asad1 kernel eliminated.

__device__ __forceinline__ float lrelu(float x){ return x > 0.f ? x : 0.2f*x; }
__device__ __forceinline__ float elu_f(float x){ return x > 0.f ? x : __expf(x) - 1.f; }
__device__ __forceinline__ unsigned short f2bf(float f){
  __hip_bfloat16 h = __float2bfloat16(f);   // RNE
  return *reinterpret_cast<unsigned short*>(&h);
}
__device__ __forceinline__ float bf2f(unsigned short u){
  return __uint_as_float(((unsigned int)u) << 16);
}
__device__ __forceinline__ float bflo(unsigned int u){ return __uint_as_float(u << 16); }
__device__ __forceinline__ float bfhi(unsigned int u){ return __uint_as_float(u & 0xffff0000u); }
__device__ __forceinline__ unsigned int packbf(float a, float b){
  return (unsigned int)f2bf(a) | ((unsigned int)f2bf(b) << 16);
}

typedef __attribute__((ext_vector_type(8))) short bf16x8;   // 8 bf16 (4 VGPRs)
typedef __attribute__((ext_vector_type(4))) float f32x4;    // 4 fp32 acc

// ---------------- input convert + deg init (fused) ----------------
__global__ void f2bf_deg_kernel(const float* __restrict__ in, unsigned short* __restrict__ out,
                                int n4, int* __restrict__ deg, int N){
  int i = blockIdx.x*256 + threadIdx.x;
  if (i < n4){
    float4 v = ((const float4*)in)[i];
    ushort4 u; u.x=f2bf(v.x); u.y=f2bf(v.y); u.z=f2bf(v.z); u.w=f2bf(v.w);
    ((ushort4*)out)[i] = u;
  }
  if (i < N) deg[i] = 1;                       // self loop
}

__global__ void deg_count_kernel(const int* __restrict__ dst, int E, int* __restrict__ deg){
  int e = blockIdx.x*blockDim.x + threadIdx.x;
  if (e < E) atomicAdd(&deg[dst[e]], 1);
}

__global__ __launch_bounds__(1024) void scan1_kernel(const int* __restrict__ deg,
                                                     int* __restrict__ rowptr1,
                                                     int* __restrict__ bsum, int N){
  __shared__ int wsum[16];
  const int tid = threadIdx.x, lane = tid & 63, w = tid >> 6;
  int i = blockIdx.x*1024 + tid;
  int x = (i < N) ? deg[i] : 0;
  #pragma unroll
  for (int d = 1; d < 64; d <<= 1){
    int y = __shfl_up(x, d);
    if (lane >= d) x += y;
  }
  if (lane == 63) wsum[w] = x;
  __syncthreads();
  if (w == 0){
    int t = (lane < 16) ? wsum[lane] : 0;
    #pragma unroll
    for (int d = 1; d < 16; d <<= 1){
      int y = __shfl_up(t, d);
      if (lane >= d && lane < 16) t += y;
    }
    if (lane < 16) wsum[lane] = t;
  }
  __syncthreads();
  if (w > 0) x += wsum[w-1];
  if (i < N) rowptr1[i] = x;
  if (tid == 1023) bsum[blockIdx.x] = x;
}

__global__ void scan2_kernel(int* __restrict__ bsum, int nb){
  int lane = threadIdx.x;
  int x = (lane < nb) ? bsum[lane] : 0;
  #pragma unroll
  for (int d = 1; d < 64; d <<= 1){
    int y = __shfl_up(x, d);
    if (lane >= d) x += y;
  }
  if (lane < nb) bsum[lane] = x;
}

__global__ void scan3_kernel(int* __restrict__ rowptr, const int* __restrict__ bsum,
                             int* __restrict__ degcur, int* __restrict__ csr, int N){
  int i = blockIdx.x*blockDim.x + threadIdx.x;
  if (i < N){
    int b = i >> 10;
    int carry = (b > 0) ? bsum[b-1] : 0;
    int rp1 = rowptr[i+1] + carry;
    rowptr[i+1] = rp1;
    int d = degcur[i];
    csr[rp1 - d] = i;        // self loop at slot 0
    degcur[i] = 1;
  }
  if (i == 0) rowptr[0] = 0;
}

__global__ void csr_scatter_kernel(const int* __restrict__ src, const int* __restrict__ dst, int E,
                                   const int* __restrict__ rowptr, int* __restrict__ cursor,
                                   int* __restrict__ csr){
  int e = blockIdx.x*blockDim.x + threadIdx.x;
  if (e < E){
    int d = dst[e];
    int pos = rowptr[d] + atomicAdd(&cursor[d], 1);
    csr[pos] = src[e];
  }
}

// ---------------- fused weight transposes ----------------
// BT1a[n][k]=W1[k][n] (head0), BT1b[n][k]=W1[k][128+n], BT2[n][k]=W2[k][n],
// BT3[n][k]=Wm1[k][n]. All bf16, row stride = K.
__global__ void wtrans_all_kernel(const float* __restrict__ W1, unsigned short* __restrict__ BT1a,
                                  unsigned short* __restrict__ BT1b,
                                  const float* __restrict__ W2, unsigned short* __restrict__ BT2,
                                  const float* __restrict__ Wm1, unsigned short* __restrict__ BT3){
  int idx = blockIdx.x*256 + threadIdx.x;
  const int S1 = 128*128, S2 = 128*256, S3 = 128*128;
  if (idx < S1){
    int n = idx >> 7, k = idx & 127;
    BT1a[idx] = f2bf(W1[(size_t)k*256 + n]);
    BT1b[idx] = f2bf(W1[(size_t)k*256 + 128 + n]);
  } else if (idx < S1 + S2){
    int j = idx - S1;
    int n = j >> 8, k = j & 255;                  // K=256, N=128
    BT2[j] = f2bf(W2[(size_t)k*128 + n]);
  } else if (idx < S1 + S2 + S3){
    int j = idx - S1 - S2;
    int n = j >> 7, k = j & 127;
    BT3[j] = f2bf(Wm1[(size_t)k*128 + n]);
  }
}

// ---------------- va vectors: va[v][k], v in {s0,s1,d0,d1} ----------------
// va_s_h[k] = sum_f W1[k, h*128+f] * a1s[h,f]  (512 threads total)
__global__ void va_kernel(const float* __restrict__ W1, const float* __restrict__ a1s,
                          const float* __restrict__ a1d, float* __restrict__ va){
  int idx = blockIdx.x*256 + threadIdx.x;
  if (idx >= 512) return;
  int v = idx >> 7, k = idx & 127;
  const float* avec = (v < 2) ? a1s : a1d;
  int head = v & 1;
  const float* wrow = W1 + (size_t)k*256 + head*128;
  const float* arow = avec + head*128;
  float s = 0.f;
  #pragma unroll 8
  for (int f = 0; f < 128; ++f) s += wrow[f]*arow[f];
  va[idx] = s;
}

// ---------------- asadx: as1/ad1 from x directly ----------------
// wave per node; lane holds 2 channels; 4 dots (s0,s1,d0,d1).
__global__ __launch_bounds__(256) void asadx_kernel(
    const float* __restrict__ x, const float* __restrict__ va,
    float* __restrict__ as_, float* __restrict__ ad_, int N)
{
  int w = threadIdx.x >> 6, lane = threadIdx.x & 63;
  int n = blockIdx.x*4 + w;
  if (n >= N) return;
  int c = lane << 1;
  float2 xv = *(const float2*)(x + (size_t)n*128 + c);
  float2 vs0 = *(const float2*)(va + c);
  float2 vs1 = *(const float2*)(va + 128 + c);
  float2 vd0 = *(const float2*)(va + 256 + c);
  float2 vd1 = *(const float2*)(va + 384 + c);
  float s0 = xv.x*vs0.x + xv.y*vs0.y;
  float s1 = xv.x*vs1.x + xv.y*vs1.y;
  float d0 = xv.x*vd0.x + xv.y*vd0.y;
  float d1 = xv.x*vd1.x + xv.y*vd1.y;
  #pragma unroll
  for (int m = 1; m <= 32; m <<= 1){
    s0 += __shfl_xor(s0, m); s1 += __shfl_xor(s1, m);
    d0 += __shfl_xor(d0, m); d1 += __shfl_xor(d1, m);
  }
  if (lane == 0){
    *(float2*)(as_ + 2*n) = make_float2(s0, s1);
    *(float2*)(ad_ + 2*n) = make_float2(d0, d1);
  }
}

// ---------------- bf16 MFMA GEMM: C[M, 0:128] = A[M,K] @ BT^T ----------------
// A bf16 row-major with row stride lda; BT bf16 [128 x K]; C row stride ldc.
// act: 0=none, 1=relu, 2=elu.
__global__ __launch_bounds__(256) void gemm_mfma_kernel(
    const unsigned short* __restrict__ A, int lda,
    const unsigned short* __restrict__ BT,
    void* __restrict__ Cv, int ldc, int M, int K,
    const float* __restrict__ bias, int act, int out_bf16)
{
  __shared__ unsigned short a_s[128*72];
  __shared__ unsigned short b_s[128*72];
  const int tid  = threadIdx.x;
  const int lane = tid & 63, wv = tid >> 6;
  const int r0 = blockIdx.y*128;
  const int mh = (wv & 1)*64, nh = (wv >> 1)*64;
  const int l15 = lane & 15, quad = lane >> 4;

  f32x4 acc[4][4];
  #pragma unroll
  for (int i = 0; i < 4; ++i)
    #pragma unroll
    for (int j = 0; j < 4; ++j)
      #pragma unroll
      for (int r = 0; r < 4; ++r) acc[i][j][r] = 0.f;

  const int srow = tid >> 3;
  const int skc  = tid & 7;

  for (int k0 = 0; k0 < K; k0 += 64){
    #pragma unroll
    for (int it = 0; it < 4; ++it){
      int row = it*32 + srow;
      int grow = r0 + row;
      uint4 v = make_uint4(0u,0u,0u,0u);
      if (grow < M) v = *(const uint4*)(A + (size_t)grow*lda + k0 + skc*8);
      *(uint4*)(&a_s[row*72 + skc*8]) = v;
    }
    #pragma unroll
    for (int it = 0; it < 4; ++it){
      int row = it*32 + srow;
      uint4 v = *(const uint4*)(BT + (size_t)row*K + k0 + skc*8);
      *(uint4*)(&b_s[row*72 + skc*8]) = v;
    }
    __syncthreads();
    #pragma unroll
    for (int ks = 0; ks < 64; ks += 32){
      bf16x8 af[4], bfr[4];
      #pragma unroll
      for (int i = 0; i < 4; ++i)
        af[i] = *(const bf16x8*)(&a_s[(mh + i*16 + l15)*72 + ks + quad*8]);
      #pragma unroll
      for (int j = 0; j < 4; ++j)
        bfr[j] = *(const bf16x8*)(&b_s[(nh + j*16 + l15)*72 + ks + quad*8]);
      #pragma unroll
      for (int i = 0; i < 4; ++i)
        #pragma unroll
        for (int j = 0; j < 4; ++j)
          acc[i][j] = __builtin_amdgcn_mfma_f32_16x16x32_bf16(bfr[j], af[i], acc[i][j], 0, 0, 0);
    }
    __syncthreads();
  }

  #pragma unroll
  for (int i = 0; i < 4; ++i){
    int m = r0 + mh + i*16 + l15;
    if (m < M){
      #pragma unroll
      for (int j = 0; j < 4; ++j){
        int n = nh + j*16 + quad*4;
        float4 bb = make_float4(0.f,0.f,0.f,0.f);
        if (bias) bb = *(const float4*)(bias + n);
        float o[4];
        #pragma unroll
        for (int r = 0; r < 4; ++r){
          float v = acc[i][j][r] + ((const float*)&bb)[r];
          if (act == 1) v = fmaxf(v, 0.f);
          else if (act == 2) v = elu_f(v);
          o[r] = v;
        }
        if (out_bf16){
          ushort4 u; u.x=f2bf(o[0]); u.y=f2bf(o[1]); u.z=f2bf(o[2]); u.w=f2bf(o[3]);
          *(ushort4*)((unsigned short*)Cv + (size_t)m*ldc + n) = u;
        } else {
          *(float4*)((float*)Cv + (size_t)m*ldc + n) = make_float4(o[0],o[1],o[2],o[3]);
        }
      }
    }
  }
}

// ---------------- asad2 (conv2 alpha dots, from h2b) ----------------
__global__ __launch_bounds__(256) void asad2_kernel(
    const unsigned short* __restrict__ h2b, const float* __restrict__ att_src,
    const float* __restrict__ att_dst, float* __restrict__ as_, float* __restrict__ ad_, int N)
{
  int w = threadIdx.x >> 6, lane = threadIdx.x & 63;
  int n = blockIdx.x*4 + w;
  if (n >= N) return;
  int c = lane << 1;
  unsigned int u = *(const unsigned int*)(h2b + (size_t)n*128 + c);
  float2 ws2 = *(const float2*)(att_src + c);
  float2 wd2 = *(const float2*)(att_dst + c);
  float vx = bflo(u), vy = bfhi(u);
  float ps = vx*ws2.x + vy*ws2.y;
  float pd = vx*wd2.x + vy*wd2.y;
  #pragma unroll
  for (int m = 1; m <= 32; m <<= 1){ ps += __shfl_xor(ps, m); pd += __shfl_xor(pd, m); }
  if (lane == 0){ as_[n] = ps; ad_[n] = pd; }
}

// ---------------- agg1x: aggregate x rows with 2-head alphas ----------------
// 4 nodes/wave, 16 lanes/node, uint4 (8 ch) per lane. Outputs xa [N,256] bf16:
// cols 0-127 = sum a0*x[src], cols 128-255 = sum a1*x[src]. No bias/act here.
__global__ __launch_bounds__(256) void agg1x_kernel(
    const unsigned short* __restrict__ xb, const float* __restrict__ as_,
    const float* __restrict__ ad_, const int* __restrict__ rowptr, const int* __restrict__ csr,
    unsigned short* __restrict__ xa, int N)
{
  const int wv = threadIdx.x >> 6, lane = threadIdx.x & 63;
  const int ql = lane & 15;
  const int n = blockIdx.x*16 + wv*4 + (lane >> 4);
  const bool valid = n < N;
  int start = 0, end = 0;
  float2 adv = make_float2(0.f, 0.f);
  if (valid){ start = rowptr[n]; end = rowptr[n+1]; adv = *(const float2*)(ad_ + 2*n); }

  int jl = start + ql;
  bool have = valid && (jl < end);
  int s_l = 0;
  float p0 = 0.f, p1 = 0.f;
  if (have){
    s_l = csr[jl];
    float2 av = *(const float2*)(as_ + 2*s_l);
    p0 = __expf(lrelu(av.x + adv.x));
    p1 = __expf(lrelu(av.y + adv.y));
  }
  float l0 = p0, l1 = p1;
  for (int j = jl + 16; j < end; j += 16){
    int s = csr[j];
    float2 av = *(const float2*)(as_ + 2*s);
    l0 += __expf(lrelu(av.x + adv.x));
    l1 += __expf(lrelu(av.y + adv.y));
  }
  #pragma unroll
  for (int msk = 1; msk <= 8; msk <<= 1){
    l0 += __shfl_xor(l0, msk);
    l1 += __shfl_xor(l1, msk);
  }
  float inv0 = 1.f / fmaxf(l0, 1e-16f);
  float inv1 = 1.f / fmaxf(l1, 1e-16f);
  float a0_l = p0 * inv0;
  float a1_l = p1 * inv1;

  float acc0[8], acc1[8];
  #pragma unroll
  for (int i = 0; i < 8; ++i){ acc0[i] = 0.f; acc1[i] = 0.f; }
  const int c = ql << 3;                           // 0..120
  const unsigned short* hp = xb + c;

  int cnt = valid ? min(16, end - start) : 0;
  for (int t = 0; t < cnt; ++t){
    int   sA  = __shfl(s_l, t, 16);
    float a0A = __shfl(a0_l, t, 16);
    float a1A = __shfl(a1_l, t, 16);
    uint4 u = *(const uint4*)(hp + (sA << 7));
    float f0 = bflo(u.x), f1 = bfhi(u.x), f2v = bflo(u.y), f3 = bfhi(u.y);
    float f4 = bflo(u.z), f5 = bfhi(u.z), f6 = bflo(u.w), f7 = bfhi(u.w);
    acc0[0] += a0A*f0; acc0[1] += a0A*f1; acc0[2] += a0A*f2v; acc0[3] += a0A*f3;
    acc0[4] += a0A*f4; acc0[5] += a0A*f5; acc0[6] += a0A*f6;  acc0[7] += a0A*f7;
    acc1[0] += a1A*f0; acc1[1] += a1A*f1; acc1[2] += a1A*f2v; acc1[3] += a1A*f3;
    acc1[4] += a1A*f4; acc1[5] += a1A*f5; acc1[6] += a1A*f6;  acc1[7] += a1A*f7;
  }
  // rare chunks beyond 16 edges
  for (int jb = start + 16; jb < end; jb += 16){
    int jl2 = jb + ql;
    int s2 = 0; float a0_2 = 0.f, a1_2 = 0.f;
    if (jl2 < end){
      s2 = csr[jl2];
      float2 av = *(const float2*)(as_ + 2*s2);
      a0_2 = __expf(lrelu(av.x + adv.x)) * inv0;
      a1_2 = __expf(lrelu(av.y + adv.y)) * inv1;
    }
    int cnt2 = min(16, end - jb);
    for (int t2 = 0; t2 < cnt2; ++t2){
      int   sA  = __shfl(s2, t2, 16);
      float a0A = __shfl(a0_2, t2, 16);
      float a1A = __shfl(a1_2, t2, 16);
      uint4 u = *(const uint4*)(hp + (sA << 7));
      float f0 = bflo(u.x), f1 = bfhi(u.x), f2v = bflo(u.y), f3 = bfhi(u.y);
      float f4 = bflo(u.z), f5 = bfhi(u.z), f6 = bflo(u.w), f7 = bfhi(u.w);
      acc0[0] += a0A*f0; acc0[1] += a0A*f1; acc0[2] += a0A*f2v; acc0[3] += a0A*f3;
      acc0[4] += a0A*f4; acc0[5] += a0A*f5; acc0[6] += a0A*f6;  acc0[7] += a0A*f7;
      acc1[0] += a1A*f0; acc1[1] += a1A*f1; acc1[2] += a1A*f2v; acc1[3] += a1A*f3;
      acc1[4] += a1A*f4; acc1[5] += a1A*f5; acc1[6] += a1A*f6;  acc1[7] += a1A*f7;
    }
  }

  if (valid){
    uint4 u0, u1;
    u0.x = packbf(acc0[0], acc0[1]); u0.y = packbf(acc0[2], acc0[3]);
    u0.z = packbf(acc0[4], acc0[5]); u0.w = packbf(acc0[6], acc0[7]);
    u1.x = packbf(acc1[0], acc1[1]); u1.y = packbf(acc1[2], acc1[3]);
    u1.z = packbf(acc1[4], acc1[5]); u1.w = packbf(acc1[6], acc1[7]);
    *(uint4*)(xa + (size_t)n*256 + c)       = u0;
    *(uint4*)(xa + (size_t)n*256 + 128 + c) = u1;
  }
}

// ---------------- agg2: 4 nodes/wave, 16 lanes/node (unchanged from R5) ----------------
__global__ __launch_bounds__(256) void agg2_kernel(
    const unsigned short* __restrict__ h2b, const float* __restrict__ as_,
    const float* __restrict__ ad_, const int* __restrict__ rowptr, const int* __restrict__ csr,
    const float* __restrict__ b2, unsigned short* __restrict__ outb, int N)
{
  const int wv = threadIdx.x >> 6, lane = threadIdx.x & 63;
  const int ql = lane & 15;
  const int n = blockIdx.x*16 + wv*4 + (lane >> 4);
  const bool valid = n < N;
  int start = 0, end = 0;
  float adn = 0.f;
  if (valid){ start = rowptr[n]; end = rowptr[n+1]; adn = ad_[n]; }

  int jl = start + ql;
  bool have = valid && (jl < end);
  int s_l = 0;
  float p_l = 0.f;
  if (have){
    s_l = csr[jl];
    p_l = __expf(lrelu(as_[s_l] + adn));
  }
  float l = p_l;
  for (int j = jl + 16; j < end; j += 16)
    l += __expf(lrelu(as_[csr[j]] + adn));
  #pragma unroll
  for (int msk = 1; msk <= 8; msk <<= 1) l += __shfl_xor(l, msk);
  float inv = 1.f / fmaxf(l, 1e-16f);
  float a_l = p_l * inv;

  float acc[8];
  #pragma unroll
  for (int i = 0; i < 8; ++i) acc[i] = 0.f;
  const int c = ql << 3;
  const unsigned short* hp = h2b + c;

  int cnt = valid ? min(16, end - start) : 0;
  int t = 0;
  for (; t + 1 < cnt; t += 2){
    int   sA = __shfl(s_l, t, 16),  sB = __shfl(s_l, t+1, 16);
    float aA = __shfl(a_l, t, 16),  aB = __shfl(a_l, t+1, 16);
    uint4 uA = *(const uint4*)(hp + (sA << 7));
    uint4 uB = *(const uint4*)(hp + (sB << 7));
    acc[0] += aA*bflo(uA.x) + aB*bflo(uB.x);
    acc[1] += aA*bfhi(uA.x) + aB*bfhi(uB.x);
    acc[2] += aA*bflo(uA.y) + aB*bflo(uB.y);
    acc[3] += aA*bfhi(uA.y) + aB*bfhi(uB.y);
    acc[4] += aA*bflo(uA.z) + aB*bflo(uB.z);
    acc[5] += aA*bfhi(uA.z) + aB*bfhi(uB.z);
    acc[6] += aA*bflo(uA.w) + aB*bflo(uB.w);
    acc[7] += aA*bfhi(uA.w) + aB*bfhi(uB.w);
  }
  if (t < cnt){
    int   sA = __shfl(s_l, t, 16);
    float aA = __shfl(a_l, t, 16);
    uint4 uA = *(const uint4*)(hp + (sA << 7));
    acc[0] += aA*bflo(uA.x); acc[1] += aA*bfhi(uA.x);
    acc[2] += aA*bflo(uA.y); acc[3] += aA*bfhi(uA.y);
    acc[4] += aA*bflo(uA.z); acc[5] += aA*bfhi(uA.z);
    acc[6] += aA*bflo(uA.w); acc[7] += aA*bfhi(uA.w);
  }
  for (int jb = start + 16; jb < end; jb += 16){
    int jl2 = jb + ql;
    int s2 = 0; float a2 = 0.f;
    if (jl2 < end){
      s2 = csr[jl2];
      a2 = __expf(lrelu(as_[s2] + adn)) * inv;
    }
    int cnt2 = min(16, end - jb);
    for (int t2 = 0; t2 < cnt2; ++t2){
      int   sA = __shfl(s2, t2, 16);
      float aA = __shfl(a2, t2, 16);
      uint4 uA = *(const uint4*)(hp + (sA << 7));
      acc[0] += aA*bflo(uA.x); acc[1] += aA*bfhi(uA.x);
      acc[2] += aA*bflo(uA.y); acc[3] += aA*bfhi(uA.y);
      acc[4] += aA*bflo(uA.z); acc[5] += aA*bfhi(uA.z);
      acc[6] += aA*bflo(uA.w); acc[7] += aA*bfhi(uA.w);
    }
  }

  if (valid){
    float4 bb0 = *(const float4*)(b2 + c);
    float4 bb1 = *(const float4*)(b2 + c + 4);
    float o[8];
    o[0]=elu_f(acc[0]+bb0.x); o[1]=elu_f(acc[1]+bb0.y);
    o[2]=elu_f(acc[2]+bb0.z); o[3]=elu_f(acc[3]+bb0.w);
    o[4]=elu_f(acc[4]+bb1.x); o[5]=elu_f(acc[5]+bb1.y);
    o[6]=elu_f(acc[6]+bb1.z); o[7]=elu_f(acc[7]+bb1.w);
    uint4 up;
    up.x = packbf(o[0], o[1]); up.y = packbf(o[2], o[3]);
    up.z = packbf(o[4], o[5]); up.w = packbf(o[6], o[7]);
    *(uint4*)(outb + (size_t)n*128 + c) = up;
  }
}

// ---------------- MLP layer 2 ----------------
__global__ __launch_bounds__(256) void mlp2_kernel(
    const float* __restrict__ hid, const float* __restrict__ Wm2,
    const float* __restrict__ bm2, float* __restrict__ out, int N)
{
  int w = threadIdx.x >> 6, lane = threadIdx.x & 63;
  int n = blockIdx.x*4 + w;
  if (n >= N) return;
  int o = lane & 7, kg = lane >> 3;
  float p = 0.f;
  #pragma unroll
  for (int i = 0; i < 16; ++i){
    int k = kg*16 + i;
    p += hid[(size_t)n*128 + k] * Wm2[k*8 + o];
  }
  p += __shfl_xor(p, 8);
  p += __shfl_xor(p, 16);
  p += __shfl_xor(p, 32);
  if (kg == 0) out[(size_t)n*8 + o] = fmaxf(p + bm2[o], 0.f);
}

extern "C" void kernel_launch(void* const* d_in, const int* in_sizes, int n_in,
                              void* d_out, int out_size, void* d_ws, size_t ws_size,
                              hipStream_t stream)
{
  (void)n_in; (void)out_size; (void)ws_size;
  const float* x   = (const float*)d_in[0];
  const int*   ei  = (const int*)d_in[1];
  const float* W1  = (const float*)d_in[2];
  const float* a1s = (const float*)d_in[3];
  const float* a1d = (const float*)d_in[4];
  const float* b1  = (const float*)d_in[5];
  const float* W2  = (const float*)d_in[6];
  const float* a2s = (const float*)d_in[7];
  const float* a2d = (const float*)d_in[8];
  const float* b2  = (const float*)d_in[9];
  const float* Wm1 = (const float*)d_in[10];
  const float* bm1 = (const float*)d_in[11];
  const float* Wm2 = (const float*)d_in[12];
  const float* bm2 = (const float*)d_in[13];
  float* out = (float*)d_out;

  const int N = in_sizes[0] / 128;
  const int E = in_sizes[1] / 2;
  const int* srcp = ei;
  const int* dstp = ei + E;

  // workspace:
  //  A [N*256 B]: xb bf16 [N,128]     -> later gb bf16 [N,128]
  //  B [N*512 B]: xa bf16 [N,256]     -> later hid fp32 [N,128]
  //  C [N*512 B]: out1b bf16 [N,256]
  //  D [N*256 B]: h2b bf16 [N,128]
  char* ws = (char*)d_ws;
  unsigned short* xb    = (unsigned short*)ws;
  unsigned short* xa    = (unsigned short*)(ws + (size_t)N*256);
  unsigned short* out1b = (unsigned short*)(ws + (size_t)N*768);
  unsigned short* h2b   = (unsigned short*)(ws + (size_t)N*1280);
  char* tail = ws + (size_t)N*1536;
  unsigned short* BT1a = (unsigned short*)tail;           // [128*128]
  unsigned short* BT1b = BT1a + 128*128;                  // [128*128]
  unsigned short* BT2  = BT1b + 128*128;                  // [128*256]
  unsigned short* BT3  = BT2 + 128*256;                   // [128*128]
  float* va   = (float*)(BT3 + 128*128);                  // [512]
  float* as1  = va + 512;
  float* ad1  = as1 + (size_t)2*N;
  float* as2  = ad1 + (size_t)2*N;
  float* ad2  = as2 + N;
  int* ideg   = (int*)(ad2 + N);
  int* rowptr = ideg + N;
  int* csr    = rowptr + N + 1;
  int* bsum   = csr + E + N;

  unsigned short* gb = xb;            // A reuse (xb dead after agg1x)
  float* hid = (float*)xa;            // B reuse (xa dead after out1 GEMMs)

  const int nb1024 = (N + 1023) / 1024;
  const int nconv4 = N*128/4;

  f2bf_deg_kernel<<<(nconv4 + 255)/256, 256, 0, stream>>>(x, xb, nconv4, ideg, N);
  deg_count_kernel<<<(E+255)/256, 256, 0, stream>>>(dstp, E, ideg);
  scan1_kernel<<<nb1024, 1024, 0, stream>>>(ideg, rowptr + 1, bsum, N);
  scan2_kernel<<<1, 64, 0, stream>>>(bsum, nb1024);
  scan3_kernel<<<nb1024, 1024, 0, stream>>>(rowptr, bsum, ideg, csr, N);
  csr_scatter_kernel<<<(E+255)/256, 256, 0, stream>>>(srcp, dstp, E, rowptr, ideg, csr);
  wtrans_all_kernel<<<(128*128 + 128*256 + 128*128 + 255)/256, 256, 0, stream>>>(
      W1, BT1a, BT1b, W2, BT2, Wm1, BT3);
  va_kernel<<<2, 256, 0, stream>>>(W1, a1s, a1d, va);

  const int gy   = (N + 127) / 128;
  const int nb4  = (N + 3) / 4;
  const int nb16 = (N + 15) / 16;

  // conv1 via linearity: alphas from x, aggregate x, then W1 + elu.
  asadx_kernel<<<nb4, 256, 0, stream>>>(x, va, as1, ad1, N);
  agg1x_kernel<<<nb16, 256, 0, stream>>>(xb, as1, ad1, rowptr, csr, xa, N);
  gemm_mfma_kernel<<<dim3(1, gy), 256, 0, stream>>>(xa,       256, BT1a, out1b,       256, N, 128, b1,       2, 1);
  gemm_mfma_kernel<<<dim3(1, gy), 256, 0, stream>>>(xa + 128, 256, BT1b, out1b + 128, 256, N, 128, b1 + 128, 2, 1);
  // conv2
  gemm_mfma_kernel<<<dim3(1, gy), 256, 0, stream>>>(out1b, 256, BT2, h2b, 128, N, 256, nullptr, 0, 1);
  asad2_kernel<<<nb4, 256, 0, stream>>>(h2b, a2s, a2d, as2, ad2, N);
  agg2_kernel<<<nb16, 256, 0, stream>>>(h2b, as2, ad2, rowptr, csr, b2, gb, N);
  // MLP
  gemm_mfma_kernel<<<dim3(1, gy), 256, 0, stream>>>(gb, 128, BT3, hid, 128, N, 128, bm1, 1, 0);
  mlp2_kernel<<<nb4, 256, 0, stream>>>(hid, Wm2, bm2, out, N);
}

// Round 7
// 300.485 us; speedup vs baseline: 1.2164x; 1.2164x over previous
//
#include <hip/hip_runtime.h>
#include <hip/hip_bf16.h>

// GATNet: 2x GATConv + 2-layer MLP.
// R6 -> R7: CSR build overhauled (old: deg_count 800k atomics + 50k scan +
// random-scatter with 64B write amplification ~80us). New bucketed build:
//   bhist   : LDS histogram -> 782 bucket counts (64 nodes/bucket)
//   bscan   : one-block scan of bucket counts
//   bscatter: LDS-aggregated scatter of packed (dstloc<<26|src) words into
//             contiguous bucket regions (dense writes, ~780 atomic-returns/blk)
//   bbuild  : block per bucket: LDS deg count + 64-scan + LDS-cursor scatter
//             into its ~4.4KB csr window (L2-hot, dense evict) + rowptr.
// Also: asadx fused into the f2bf conversion pass (saves a 25.6MB read).

__device__ __forceinline__ float lrelu(float x){ return x > 0.f ? x : 0.2f*x; }
__device__ __forceinline__ float elu_f(float x){ return x > 0.f ? x : __expf(x) - 1.f; }
__device__ __forceinline__ unsigned short f2bf(float f){
  __hip_bfloat16 h = __float2bfloat16(f);   // RNE
  return *reinterpret_cast<unsigned short*>(&h);
}
__device__ __forceinline__ float bflo(unsigned int u){ return __uint_as_float(u << 16); }
__device__ __forceinline__ float bfhi(unsigned int u){ return __uint_as_float(u & 0xffff0000u); }
__device__ __forceinline__ unsigned int packbf(float a, float b){
  return (unsigned int)f2bf(a) | ((unsigned int)f2bf(b) << 16);
}

typedef __attribute__((ext_vector_type(8))) short bf16x8;
typedef __attribute__((ext_vector_type(4))) float f32x4;

// ---------------- fused: x->bf16 convert + conv1 alpha dots + zero bucket arrays ----------------
// thread i handles 4 floats of x; 32-lane group = one node row (128 ch).
__global__ __launch_bounds__(256) void f2bf_fuse_kernel(
    const float* __restrict__ x, unsigned short* __restrict__ xb, int N,
    const float* __restrict__ va, float* __restrict__ as1, float* __restrict__ ad1,
    int* __restrict__ bcount, int* __restrict__ gcur, int NB)
{
  int i = blockIdx.x*256 + threadIdx.x;
  int total = N*32;
  float4 v = make_float4(0.f,0.f,0.f,0.f);
  if (i < total){
    v = ((const float4*)x)[i];
    ushort4 u; u.x=f2bf(v.x); u.y=f2bf(v.y); u.z=f2bf(v.z); u.w=f2bf(v.w);
    ((ushort4*)xb)[i] = u;
  }
  int c = (i & 31) << 2;
  float4 vs0 = *(const float4*)(va + c);
  float4 vs1 = *(const float4*)(va + 128 + c);
  float4 vd0 = *(const float4*)(va + 256 + c);
  float4 vd1 = *(const float4*)(va + 384 + c);
  float s0 = v.x*vs0.x + v.y*vs0.y + v.z*vs0.z + v.w*vs0.w;
  float s1 = v.x*vs1.x + v.y*vs1.y + v.z*vs1.z + v.w*vs1.w;
  float d0 = v.x*vd0.x + v.y*vd0.y + v.z*vd0.z + v.w*vd0.w;
  float d1 = v.x*vd1.x + v.y*vd1.y + v.z*vd1.z + v.w*vd1.w;
  #pragma unroll
  for (int m = 1; m <= 16; m <<= 1){
    s0 += __shfl_xor(s0, m); s1 += __shfl_xor(s1, m);
    d0 += __shfl_xor(d0, m); d1 += __shfl_xor(d1, m);
  }
  if ((i & 31) == 0 && i < total){
    int n = i >> 5;
    *(float2*)(as1 + 2*n) = make_float2(s0, s1);
    *(float2*)(ad1 + 2*n) = make_float2(d0, d1);
  }
  if (i < NB){ bcount[i] = 0; gcur[i] = 0; }
}

// ---------------- va vectors: va[v][k], v in {s0,s1,d0,d1} ----------------
__global__ void va_kernel(const float* __restrict__ W1, const float* __restrict__ a1s,
                          const float* __restrict__ a1d, float* __restrict__ va){
  int idx = blockIdx.x*256 + threadIdx.x;
  if (idx >= 512) return;
  int v = idx >> 7, k = idx & 127;
  const float* avec = (v < 2) ? a1s : a1d;
  int head = v & 1;
  const float* wrow = W1 + (size_t)k*256 + head*128;
  const float* arow = avec + head*128;
  float s = 0.f;
  #pragma unroll 8
  for (int f = 0; f < 128; ++f) s += wrow[f]*arow[f];
  va[idx] = s;
}

// ---------------- bucketed CSR build ----------------
// bucket = dst >> 6 (64 nodes per bucket), NB <= 1024.
__global__ __launch_bounds__(1024) void bhist_kernel(const int* __restrict__ dst, int E,
                                                     int* __restrict__ bcount, int NB){
  __shared__ int h[1024];
  for (int i = threadIdx.x; i < NB; i += 1024) h[i] = 0;
  __syncthreads();
  for (int e = blockIdx.x*1024 + threadIdx.x; e < E; e += gridDim.x*1024)
    atomicAdd(&h[dst[e] >> 6], 1);
  __syncthreads();
  for (int i = threadIdx.x; i < NB; i += 1024)
    if (h[i]) atomicAdd(&bcount[i], h[i]);
}

__global__ __launch_bounds__(1024) void bscan_kernel(const int* __restrict__ bcount,
                                                     int* __restrict__ boff, int NB){
  __shared__ int s[1024];
  int t = threadIdx.x;
  int mine = (t < NB) ? bcount[t] : 0;
  s[t] = mine;
  __syncthreads();
  for (int d = 1; d < 1024; d <<= 1){
    int v = (t >= d) ? s[t-d] : 0;
    __syncthreads();
    s[t] += v;
    __syncthreads();
  }
  if (t < NB) boff[t] = s[t] - mine;    // exclusive
  if (t == NB-1) boff[NB] = s[t];       // total = E
}

// packed word: (dstloc << 26) | src   (requires src < 2^26)
__global__ __launch_bounds__(256) void bscatter_kernel(
    const int* __restrict__ src, const int* __restrict__ dst, int E,
    const int* __restrict__ boff, int* __restrict__ gcur,
    unsigned int* __restrict__ pairs, int NB)
{
  __shared__ int h[1024];
  __shared__ int runbase[1024];
  const int t = threadIdx.x;
  const int e0 = blockIdx.x * 4096;
  for (int i = t; i < NB; i += 256) h[i] = 0;
  __syncthreads();
  int myb[16]; unsigned int myw[16];
  #pragma unroll
  for (int q = 0; q < 16; ++q){
    int e = e0 + q*256 + t;
    int b = -1; unsigned int w = 0;
    if (e < E){
      int d = dst[e];
      b = d >> 6;
      w = ((unsigned int)(d & 63) << 26) | (unsigned int)src[e];
      atomicAdd(&h[b], 1);
    }
    myb[q] = b; myw[q] = w;
  }
  __syncthreads();
  for (int i = t; i < NB; i += 256)
    runbase[i] = h[i] ? atomicAdd(&gcur[i], h[i]) : 0;
  __syncthreads();
  for (int i = t; i < NB; i += 256) h[i] = 0;
  __syncthreads();
  #pragma unroll
  for (int q = 0; q < 16; ++q){
    if (myb[q] >= 0){
      int off = atomicAdd(&h[myb[q]], 1);
      pairs[(size_t)boff[myb[q]] + runbase[myb[q]] + off] = myw[q];
    }
  }
}

// one block per bucket: build rowptr + csr segment (self loop in slot 0).
__global__ __launch_bounds__(256) void bbuild_kernel(
    const unsigned int* __restrict__ pairs, const int* __restrict__ boff,
    int* __restrict__ rowptr, int* __restrict__ csr, int N)
{
  __shared__ int deg[64], offs[64], cur[64];
  const int b = blockIdx.x;
  const int t = threadIdx.x;
  const int n0 = b << 6;
  const int nNodes = min(64, N - n0);
  const int p0 = boff[b], p1 = boff[b+1];
  const int base = p0 + n0;                 // self loops of preceding buckets = n0
  if (t < 64) deg[t] = (t < nNodes) ? 1 : 0;
  __syncthreads();
  for (int i = p0 + t; i < p1; i += 256)
    atomicAdd(&deg[pairs[i] >> 26], 1);
  __syncthreads();
  if (t < 64){
    int x = deg[t];
    #pragma unroll
    for (int d = 1; d < 64; d <<= 1){
      int y = __shfl_up(x, d);
      if (t >= d) x += y;
    }
    offs[t] = x - deg[t];                   // exclusive
    cur[t] = 1;
    if (t < nNodes){
      rowptr[n0 + t + 1] = base + x;        // inclusive end
      csr[base + x - deg[t]] = n0 + t;      // self loop
    }
    if (b == 0 && t == 0) rowptr[0] = 0;
  }
  __syncthreads();
  for (int i = p0 + t; i < p1; i += 256){
    unsigned int w = pairs[i];
    int dl = w >> 26;
    int s  = (int)(w & 0x03ffffffu);
    int off = atomicAdd(&cur[dl], 1);
    csr[base + offs[dl] + off] = s;
  }
}

// ---------------- fused weight transposes ----------------
__global__ void wtrans_all_kernel(const float* __restrict__ W1, unsigned short* __restrict__ BT1a,
                                  unsigned short* __restrict__ BT1b,
                                  const float* __restrict__ W2, unsigned short* __restrict__ BT2,
                                  const float* __restrict__ Wm1, unsigned short* __restrict__ BT3){
  int idx = blockIdx.x*256 + threadIdx.x;
  const int S1 = 128*128, S2 = 128*256, S3 = 128*128;
  if (idx < S1){
    int n = idx >> 7, k = idx & 127;
    BT1a[idx] = f2bf(W1[(size_t)k*256 + n]);
    BT1b[idx] = f2bf(W1[(size_t)k*256 + 128 + n]);
  } else if (idx < S1 + S2){
    int j = idx - S1;
    int n = j >> 8, k = j & 255;
    BT2[j] = f2bf(W2[(size_t)k*128 + n]);
  } else if (idx < S1 + S2 + S3){
    int j = idx - S1 - S2;
    int n = j >> 7, k = j & 127;
    BT3[j] = f2bf(Wm1[(size_t)k*128 + n]);
  }
}

// ---------------- bf16 MFMA GEMM: C[M, 0:128] = A[M,K] @ BT^T ----------------
__global__ __launch_bounds__(256) void gemm_mfma_kernel(
    const unsigned short* __restrict__ A, int lda,
    const unsigned short* __restrict__ BT,
    void* __restrict__ Cv, int ldc, int M, int K,
    const float* __restrict__ bias, int act, int out_bf16)
{
  __shared__ unsigned short a_s[128*72];
  __shared__ unsigned short b_s[128*72];
  const int tid  = threadIdx.x;
  const int lane = tid & 63, wv = tid >> 6;
  const int r0 = blockIdx.y*128;
  const int mh = (wv & 1)*64, nh = (wv >> 1)*64;
  const int l15 = lane & 15, quad = lane >> 4;

  f32x4 acc[4][4];
  #pragma unroll
  for (int i = 0; i < 4; ++i)
    #pragma unroll
    for (int j = 0; j < 4; ++j)
      #pragma unroll
      for (int r = 0; r < 4; ++r) acc[i][j][r] = 0.f;

  const int srow = tid >> 3;
  const int skc  = tid & 7;

  for (int k0 = 0; k0 < K; k0 += 64){
    #pragma unroll
    for (int it = 0; it < 4; ++it){
      int row = it*32 + srow;
      int grow = r0 + row;
      uint4 v = make_uint4(0u,0u,0u,0u);
      if (grow < M) v = *(const uint4*)(A + (size_t)grow*lda + k0 + skc*8);
      *(uint4*)(&a_s[row*72 + skc*8]) = v;
    }
    #pragma unroll
    for (int it = 0; it < 4; ++it){
      int row = it*32 + srow;
      uint4 v = *(const uint4*)(BT + (size_t)row*K + k0 + skc*8);
      *(uint4*)(&b_s[row*72 + skc*8]) = v;
    }
    __syncthreads();
    #pragma unroll
    for (int ks = 0; ks < 64; ks += 32){
      bf16x8 af[4], bfr[4];
      #pragma unroll
      for (int i = 0; i < 4; ++i)
        af[i] = *(const bf16x8*)(&a_s[(mh + i*16 + l15)*72 + ks + quad*8]);
      #pragma unroll
      for (int j = 0; j < 4; ++j)
        bfr[j] = *(const bf16x8*)(&b_s[(nh + j*16 + l15)*72 + ks + quad*8]);
      #pragma unroll
      for (int i = 0; i < 4; ++i)
        #pragma unroll
        for (int j = 0; j < 4; ++j)
          acc[i][j] = __builtin_amdgcn_mfma_f32_16x16x32_bf16(bfr[j], af[i], acc[i][j], 0, 0, 0);
    }
    __syncthreads();
  }

  #pragma unroll
  for (int i = 0; i < 4; ++i){
    int m = r0 + mh + i*16 + l15;
    if (m < M){
      #pragma unroll
      for (int j = 0; j < 4; ++j){
        int n = nh + j*16 + quad*4;
        float4 bb = make_float4(0.f,0.f,0.f,0.f);
        if (bias) bb = *(const float4*)(bias + n);
        float o[4];
        #pragma unroll
        for (int r = 0; r < 4; ++r){
          float v = acc[i][j][r] + ((const float*)&bb)[r];
          if (act == 1) v = fmaxf(v, 0.f);
          else if (act == 2) v = elu_f(v);
          o[r] = v;
        }
        if (out_bf16){
          ushort4 u; u.x=f2bf(o[0]); u.y=f2bf(o[1]); u.z=f2bf(o[2]); u.w=f2bf(o[3]);
          *(ushort4*)((unsigned short*)Cv + (size_t)m*ldc + n) = u;
        } else {
          *(float4*)((float*)Cv + (size_t)m*ldc + n) = make_float4(o[0],o[1],o[2],o[3]);
        }
      }
    }
  }
}

// ---------------- asad2 (conv2 alpha dots, from h2b) ----------------
__global__ __launch_bounds__(256) void asad2_kernel(
    const unsigned short* __restrict__ h2b, const float* __restrict__ att_src,
    const float* __restrict__ att_dst, float* __restrict__ as_, float* __restrict__ ad_, int N)
{
  int w = threadIdx.x >> 6, lane = threadIdx.x & 63;
  int n = blockIdx.x*4 + w;
  if (n >= N) return;
  int c = lane << 1;
  unsigned int u = *(const unsigned int*)(h2b + (size_t)n*128 + c);
  float2 ws2 = *(const float2*)(att_src + c);
  float2 wd2 = *(const float2*)(att_dst + c);
  float vx = bflo(u), vy = bfhi(u);
  float ps = vx*ws2.x + vy*ws2.y;
  float pd = vx*wd2.x + vy*wd2.y;
  #pragma unroll
  for (int m = 1; m <= 32; m <<= 1){ ps += __shfl_xor(ps, m); pd += __shfl_xor(pd, m); }
  if (lane == 0){ as_[n] = ps; ad_[n] = pd; }
}

// ---------------- agg1x: aggregate x rows with 2-head alphas ----------------
__global__ __launch_bounds__(256) void agg1x_kernel(
    const unsigned short* __restrict__ xb, const float* __restrict__ as_,
    const float* __restrict__ ad_, const int* __restrict__ rowptr, const int* __restrict__ csr,
    unsigned short* __restrict__ xa, int N)
{
  const int wv = threadIdx.x >> 6, lane = threadIdx.x & 63;
  const int ql = lane & 15;
  const int n = blockIdx.x*16 + wv*4 + (lane >> 4);
  const bool valid = n < N;
  int start = 0, end = 0;
  float2 adv = make_float2(0.f, 0.f);
  if (valid){ start = rowptr[n]; end = rowptr[n+1]; adv = *(const float2*)(ad_ + 2*n); }

  int jl = start + ql;
  bool have = valid && (jl < end);
  int s_l = 0;
  float p0 = 0.f, p1 = 0.f;
  if (have){
    s_l = csr[jl];
    float2 av = *(const float2*)(as_ + 2*s_l);
    p0 = __expf(lrelu(av.x + adv.x));
    p1 = __expf(lrelu(av.y + adv.y));
  }
  float l0 = p0, l1 = p1;
  for (int j = jl + 16; j < end; j += 16){
    int s = csr[j];
    float2 av = *(const float2*)(as_ + 2*s);
    l0 += __expf(lrelu(av.x + adv.x));
    l1 += __expf(lrelu(av.y + adv.y));
  }
  #pragma unroll
  for (int msk = 1; msk <= 8; msk <<= 1){
    l0 += __shfl_xor(l0, msk);
    l1 += __shfl_xor(l1, msk);
  }
  float inv0 = 1.f / fmaxf(l0, 1e-16f);
  float inv1 = 1.f / fmaxf(l1, 1e-16f);
  float a0_l = p0 * inv0;
  float a1_l = p1 * inv1;

  float acc0[8], acc1[8];
  #pragma unroll
  for (int i = 0; i < 8; ++i){ acc0[i] = 0.f; acc1[i] = 0.f; }
  const int c = ql << 3;
  const unsigned short* hp = xb + c;

  int cnt = valid ? min(16, end - start) : 0;
  for (int t = 0; t < cnt; ++t){
    int   sA  = __shfl(s_l, t, 16);
    float a0A = __shfl(a0_l, t, 16);
    float a1A = __shfl(a1_l, t, 16);
    uint4 u = *(const uint4*)(hp + (sA << 7));
    float f0 = bflo(u.x), f1 = bfhi(u.x), f2v = bflo(u.y), f3 = bfhi(u.y);
    float f4 = bflo(u.z), f5 = bfhi(u.z), f6 = bflo(u.w), f7 = bfhi(u.w);
    acc0[0] += a0A*f0; acc0[1] += a0A*f1; acc0[2] += a0A*f2v; acc0[3] += a0A*f3;
    acc0[4] += a0A*f4; acc0[5] += a0A*f5; acc0[6] += a0A*f6;  acc0[7] += a0A*f7;
    acc1[0] += a1A*f0; acc1[1] += a1A*f1; acc1[2] += a1A*f2v; acc1[3] += a1A*f3;
    acc1[4] += a1A*f4; acc1[5] += a1A*f5; acc1[6] += a1A*f6;  acc1[7] += a1A*f7;
  }
  for (int jb = start + 16; jb < end; jb += 16){
    int jl2 = jb + ql;
    int s2 = 0; float a0_2 = 0.f, a1_2 = 0.f;
    if (jl2 < end){
      s2 = csr[jl2];
      float2 av = *(const float2*)(as_ + 2*s2);
      a0_2 = __expf(lrelu(av.x + adv.x)) * inv0;
      a1_2 = __expf(lrelu(av.y + adv.y)) * inv1;
    }
    int cnt2 = min(16, end - jb);
    for (int t2 = 0; t2 < cnt2; ++t2){
      int   sA  = __shfl(s2, t2, 16);
      float a0A = __shfl(a0_2, t2, 16);
      float a1A = __shfl(a1_2, t2, 16);
      uint4 u = *(const uint4*)(hp + (sA << 7));
      float f0 = bflo(u.x), f1 = bfhi(u.x), f2v = bflo(u.y), f3 = bfhi(u.y);
      float f4 = bflo(u.z), f5 = bfhi(u.z), f6 = bflo(u.w), f7 = bfhi(u.w);
      acc0[0] += a0A*f0; acc0[1] += a0A*f1; acc0[2] += a0A*f2v; acc0[3] += a0A*f3;
      acc0[4] += a0A*f4; acc0[5] += a0A*f5; acc0[6] += a0A*f6;  acc0[7] += a0A*f7;
      acc1[0] += a1A*f0; acc1[1] += a1A*f1; acc1[2] += a1A*f2v; acc1[3] += a1A*f3;
      acc1[4] += a1A*f4; acc1[5] += a1A*f5; acc1[6] += a1A*f6;  acc1[7] += a1A*f7;
    }
  }

  if (valid){
    uint4 u0, u1;
    u0.x = packbf(acc0[0], acc0[1]); u0.y = packbf(acc0[2], acc0[3]);
    u0.z = packbf(acc0[4], acc0[5]); u0.w = packbf(acc0[6], acc0[7]);
    u1.x = packbf(acc1[0], acc1[1]); u1.y = packbf(acc1[2], acc1[3]);
    u1.z = packbf(acc1[4], acc1[5]); u1.w = packbf(acc1[6], acc1[7]);
    *(uint4*)(xa + (size_t)n*256 + c)       = u0;
    *(uint4*)(xa + (size_t)n*256 + 128 + c) = u1;
  }
}

// ---------------- agg2: 4 nodes/wave, 16 lanes/node ----------------
__global__ __launch_bounds__(256) void agg2_kernel(
    const unsigned short* __restrict__ h2b, const float* __restrict__ as_,
    const float* __restrict__ ad_, const int* __restrict__ rowptr, const int* __restrict__ csr,
    const float* __restrict__ b2, unsigned short* __restrict__ outb, int N)
{
  const int wv = threadIdx.x >> 6, lane = threadIdx.x & 63;
  const int ql = lane & 15;
  const int n = blockIdx.x*16 + wv*4 + (lane >> 4);
  const bool valid = n < N;
  int start = 0, end = 0;
  float adn = 0.f;
  if (valid){ start = rowptr[n]; end = rowptr[n+1]; adn = ad_[n]; }

  int jl = start + ql;
  bool have = valid && (jl < end);
  int s_l = 0;
  float p_l = 0.f;
  if (have){
    s_l = csr[jl];
    p_l = __expf(lrelu(as_[s_l] + adn));
  }
  float l = p_l;
  for (int j = jl + 16; j < end; j += 16)
    l += __expf(lrelu(as_[csr[j]] + adn));
  #pragma unroll
  for (int msk = 1; msk <= 8; msk <<= 1) l += __shfl_xor(l, msk);
  float inv = 1.f / fmaxf(l, 1e-16f);
  float a_l = p_l * inv;

  float acc[8];
  #pragma unroll
  for (int i = 0; i < 8; ++i) acc[i] = 0.f;
  const int c = ql << 3;
  const unsigned short* hp = h2b + c;

  int cnt = valid ? min(16, end - start) : 0;
  int t = 0;
  for (; t + 1 < cnt; t += 2){
    int   sA = __shfl(s_l, t, 16),  sB = __shfl(s_l, t+1, 16);
    float aA = __shfl(a_l, t, 16),  aB = __shfl(a_l, t+1, 16);
    uint4 uA = *(const uint4*)(hp + (sA << 7));
    uint4 uB = *(const uint4*)(hp + (sB << 7));
    acc[0] += aA*bflo(uA.x) + aB*bflo(uB.x);
    acc[1] += aA*bfhi(uA.x) + aB*bfhi(uB.x);
    acc[2] += aA*bflo(uA.y) + aB*bflo(uB.y);
    acc[3] += aA*bfhi(uA.y) + aB*bfhi(uB.y);
    acc[4] += aA*bflo(uA.z) + aB*bflo(uB.z);
    acc[5] += aA*bfhi(uA.z) + aB*bfhi(uB.z);
    acc[6] += aA*bflo(uA.w) + aB*bflo(uB.w);
    acc[7] += aA*bfhi(uA.w) + aB*bfhi(uB.w);
  }
  if (t < cnt){
    int   sA = __shfl(s_l, t, 16);
    float aA = __shfl(a_l, t, 16);
    uint4 uA = *(const uint4*)(hp + (sA << 7));
    acc[0] += aA*bflo(uA.x); acc[1] += aA*bfhi(uA.x);
    acc[2] += aA*bflo(uA.y); acc[3] += aA*bfhi(uA.y);
    acc[4] += aA*bflo(uA.z); acc[5] += aA*bfhi(uA.z);
    acc[6] += aA*bflo(uA.w); acc[7] += aA*bfhi(uA.w);
  }
  for (int jb = start + 16; jb < end; jb += 16){
    int jl2 = jb + ql;
    int s2 = 0; float a2 = 0.f;
    if (jl2 < end){
      s2 = csr[jl2];
      a2 = __expf(lrelu(as_[s2] + adn)) * inv;
    }
    int cnt2 = min(16, end - jb);
    for (int t2 = 0; t2 < cnt2; ++t2){
      int   sA = __shfl(s2, t2, 16);
      float aA = __shfl(a2, t2, 16);
      uint4 uA = *(const uint4*)(hp + (sA << 7));
      acc[0] += aA*bflo(uA.x); acc[1] += aA*bfhi(uA.x);
      acc[2] += aA*bflo(uA.y); acc[3] += aA*bfhi(uA.y);
      acc[4] += aA*bflo(uA.z); acc[5] += aA*bfhi(uA.z);
      acc[6] += aA*bflo(uA.w); acc[7] += aA*bfhi(uA.w);
    }
  }

  if (valid){
    float4 bb0 = *(const float4*)(b2 + c);
    float4 bb1 = *(const float4*)(b2 + c + 4);
    float o[8];
    o[0]=elu_f(acc[0]+bb0.x); o[1]=elu_f(acc[1]+bb0.y);
    o[2]=elu_f(acc[2]+bb0.z); o[3]=elu_f(acc[3]+bb0.w);
    o[4]=elu_f(acc[4]+bb1.x); o[5]=elu_f(acc[5]+bb1.y);
    o[6]=elu_f(acc[6]+bb1.z); o[7]=elu_f(acc[7]+bb1.w);
    uint4 up;
    up.x = packbf(o[0], o[1]); up.y = packbf(o[2], o[3]);
    up.z = packbf(o[4], o[5]); up.w = packbf(o[6], o[7]);
    *(uint4*)(outb + (size_t)n*128 + c) = up;
  }
}

// ---------------- MLP layer 2 ----------------
__global__ __launch_bounds__(256) void mlp2_kernel(
    const float* __restrict__ hid, const float* __restrict__ Wm2,
    const float* __restrict__ bm2, float* __restrict__ out, int N)
{
  int w = threadIdx.x >> 6, lane = threadIdx.x & 63;
  int n = blockIdx.x*4 + w;
  if (n >= N) return;
  int o = lane & 7, kg = lane >> 3;
  float p = 0.f;
  #pragma unroll
  for (int i = 0; i < 16; ++i){
    int k = kg*16 + i;
    p += hid[(size_t)n*128 + k] * Wm2[k*8 + o];
  }
  p += __shfl_xor(p, 8);
  p += __shfl_xor(p, 16);
  p += __shfl_xor(p, 32);
  if (kg == 0) out[(size_t)n*8 + o] = fmaxf(p + bm2[o], 0.f);
}

extern "C" void kernel_launch(void* const* d_in, const int* in_sizes, int n_in,
                              void* d_out, int out_size, void* d_ws, size_t ws_size,
                              hipStream_t stream)
{
  (void)n_in; (void)out_size; (void)ws_size;
  const float* x   = (const float*)d_in[0];
  const int*   ei  = (const int*)d_in[1];
  const float* W1  = (const float*)d_in[2];
  const float* a1s = (const float*)d_in[3];
  const float* a1d = (const float*)d_in[4];
  const float* b1  = (const float*)d_in[5];
  const float* W2  = (const float*)d_in[6];
  const float* a2s = (const float*)d_in[7];
  const float* a2d = (const float*)d_in[8];
  const float* b2  = (const float*)d_in[9];
  const float* Wm1 = (const float*)d_in[10];
  const float* bm1 = (const float*)d_in[11];
  const float* Wm2 = (const float*)d_in[12];
  const float* bm2 = (const float*)d_in[13];
  float* out = (float*)d_out;

  const int N = in_sizes[0] / 128;
  const int E = in_sizes[1] / 2;
  const int NB = (N + 63) >> 6;       // buckets of 64 nodes (<=1024 for N<=65536)
  const int* srcp = ei;
  const int* dstp = ei + E;

  // workspace:
  //  A [N*256 B]: xb bf16 [N,128]     -> later gb bf16 [N,128]
  //  B [N*512 B]: xa bf16 [N,256]     -> later hid fp32 [N,128]
  //  C [N*512 B]: out1b bf16 [N,256]
  //  D [N*256 B]: h2b bf16 [N,128]
  char* ws = (char*)d_ws;
  unsigned short* xb    = (unsigned short*)ws;
  unsigned short* xa    = (unsigned short*)(ws + (size_t)N*256);
  unsigned short* out1b = (unsigned short*)(ws + (size_t)N*768);
  unsigned short* h2b   = (unsigned short*)(ws + (size_t)N*1280);
  char* tail = ws + (size_t)N*1536;
  unsigned short* BT1a = (unsigned short*)tail;           // [128*128]
  unsigned short* BT1b = BT1a + 128*128;
  unsigned short* BT2  = BT1b + 128*128;                  // [128*256]
  unsigned short* BT3  = BT2 + 128*256;                   // [128*128]
  float* va   = (float*)(BT3 + 128*128);                  // [512]
  float* as1  = va + 512;
  float* ad1  = as1 + (size_t)2*N;
  float* as2  = ad1 + (size_t)2*N;
  float* ad2  = as2 + N;
  int* bcount = (int*)(ad2 + N);          // [1024]
  int* boff   = bcount + 1024;            // [1025]
  int* gcur   = boff + 1032;              // [1024]
  int* rowptr = gcur + 1024;              // [N+1]
  int* csr    = rowptr + N + 1;           // [E+N]
  unsigned int* pairs = (unsigned int*)(csr + E + N);   // [E]

  unsigned short* gb = xb;            // A reuse (xb dead after agg1x)
  float* hid = (float*)xa;            // B reuse (xa dead after conv1 GEMMs)

  // prep: va first (f2bf_fuse consumes it), weights anytime before GEMMs
  va_kernel<<<2, 256, 0, stream>>>(W1, a1s, a1d, va);
  f2bf_fuse_kernel<<<(N*32 + 255)/256, 256, 0, stream>>>(x, xb, N, va, as1, ad1,
                                                         bcount, gcur, NB);
  // bucketed CSR build
  bhist_kernel<<<64, 1024, 0, stream>>>(dstp, E, bcount, NB);
  bscan_kernel<<<1, 1024, 0, stream>>>(bcount, boff, NB);
  bscatter_kernel<<<(E + 4095)/4096, 256, 0, stream>>>(srcp, dstp, E, boff, gcur, pairs, NB);
  bbuild_kernel<<<NB, 256, 0, stream>>>(pairs, boff, rowptr, csr, N);
  wtrans_all_kernel<<<(128*128 + 128*256 + 128*128 + 255)/256, 256, 0, stream>>>(
      W1, BT1a, BT1b, W2, BT2, Wm1, BT3);

  const int gy   = (N + 127) / 128;
  const int nb4  = (N + 3) / 4;
  const int nb16 = (N + 15) / 16;

  // conv1 via linearity: aggregate x, then W1 + elu.
  agg1x_kernel<<<nb16, 256, 0, stream>>>(xb, as1, ad1, rowptr, csr, xa, N);
  gemm_mfma_kernel<<<dim3(1, gy), 256, 0, stream>>>(xa,       256, BT1a, out1b,       256, N, 128, b1,       2, 1);
  gemm_mfma_kernel<<<dim3(1, gy), 256, 0, stream>>>(xa + 128, 256, BT1b, out1b + 128, 256, N, 128, b1 + 128, 2, 1);
  // conv2
  gemm_mfma_kernel<<<dim3(1, gy), 256, 0, stream>>>(out1b, 256, BT2, h2b, 128, N, 256, nullptr, 0, 1);
  asad2_kernel<<<nb4, 256, 0, stream>>>(h2b, a2s, a2d, as2, ad2, N);
  agg2_kernel<<<nb16, 256, 0, stream>>>(h2b, as2, ad2, rowptr, csr, b2, gb, N);
  // MLP
  gemm_mfma_kernel<<<dim3(1, gy), 256, 0, stream>>>(gb, 128, BT3, hid, 128, N, 128, bm1, 1, 0);
  mlp2_kernel<<<nb4, 256, 0, stream>>>(hid, Wm2, bm2, out, N);
}

// Round 8
// 267.413 us; speedup vs baseline: 1.3668x; 1.1237x over previous
//
#include <hip/hip_runtime.h>
#include <hip/hip_bf16.h>

// GATNet: 2x GATConv + 2-layer MLP.
// R7 -> R8: dispatch-count reduction 15 -> 10 + epilogue fusions.
//  - prep_kernel: va + 3 weight transposes + zero bucket arrays (one launch)
//  - f2bf_hist: x->bf16 + conv1 alpha dots + edge histogram (block-role split)
//  - gemm_conv1: both head-halves in one launch (grid.x = 2)
//  - gemm_conv2: asad2 fused into epilogue (shuffle + LDS cross-wave reduce)
//  - gemm_mlp:   mlp2 fused into epilogue (Wm2 in LDS) -> writes d_out, no hid
// CSR bucketed build + agg kernels unchanged from R7.

__device__ __forceinline__ float lrelu(float x){ return x > 0.f ? x : 0.2f*x; }
__device__ __forceinline__ float elu_f(float x){ return x > 0.f ? x : __expf(x) - 1.f; }
__device__ __forceinline__ unsigned short f2bf(float f){
  __hip_bfloat16 h = __float2bfloat16(f);   // RNE
  return *reinterpret_cast<unsigned short*>(&h);
}
__device__ __forceinline__ float bflo(unsigned int u){ return __uint_as_float(u << 16); }
__device__ __forceinline__ float bfhi(unsigned int u){ return __uint_as_float(u & 0xffff0000u); }
__device__ __forceinline__ unsigned int packbf(float a, float b){
  return (unsigned int)f2bf(a) | ((unsigned int)f2bf(b) << 16);
}

typedef __attribute__((ext_vector_type(8))) short bf16x8;
typedef __attribute__((ext_vector_type(4))) float f32x4;

// ---------------- prep: va + weight transposes + zero bucket arrays ----------------
__global__ void prep_kernel(const float* __restrict__ W1, unsigned short* __restrict__ BT1a,
                            unsigned short* __restrict__ BT1b,
                            const float* __restrict__ W2, unsigned short* __restrict__ BT2,
                            const float* __restrict__ Wm1, unsigned short* __restrict__ BT3,
                            const float* __restrict__ a1s, const float* __restrict__ a1d,
                            float* __restrict__ va, int* __restrict__ bcount,
                            int* __restrict__ gcur, int NB){
  int idx = blockIdx.x*256 + threadIdx.x;
  const int S1 = 128*128, S2 = 128*256, S3 = 128*128;
  if (idx < S1){
    int n = idx >> 7, k = idx & 127;
    BT1a[idx] = f2bf(W1[(size_t)k*256 + n]);
    BT1b[idx] = f2bf(W1[(size_t)k*256 + 128 + n]);
  } else if (idx < S1 + S2){
    int j = idx - S1;
    int n = j >> 8, k = j & 255;
    BT2[j] = f2bf(W2[(size_t)k*128 + n]);
  } else if (idx < S1 + S2 + S3){
    int j = idx - S1 - S2;
    int n = j >> 7, k = j & 127;
    BT3[j] = f2bf(Wm1[(size_t)k*128 + n]);
  } else if (idx < S1 + S2 + S3 + 512){
    int j = idx - S1 - S2 - S3;
    int v = j >> 7, k = j & 127;
    const float* avec = (v < 2) ? a1s : a1d;
    int head = v & 1;
    const float* wrow = W1 + (size_t)k*256 + head*128;
    const float* arow = avec + head*128;
    float s = 0.f;
    #pragma unroll 8
    for (int f = 0; f < 128; ++f) s += wrow[f]*arow[f];
    va[j] = s;
  } else if (idx < S1 + S2 + S3 + 512 + 2048){
    int z = idx - (S1 + S2 + S3 + 512);
    if (z < 1024){ if (z < NB) bcount[z] = 0; }
    else { z -= 1024; if (z < NB) gcur[z] = 0; }
  }
}

// ---------------- f2bf + conv1 alpha dots + edge histogram (block-role split) ----------------
__global__ __launch_bounds__(256) void f2bf_hist_kernel(
    const float* __restrict__ x, unsigned short* __restrict__ xb, int N,
    const float* __restrict__ va, float* __restrict__ as1, float* __restrict__ ad1,
    const int* __restrict__ dst, int E, int* __restrict__ bcount, int NB, int nbConv)
{
  __shared__ int h[1024];
  if ((int)blockIdx.x < nbConv){
    int i = blockIdx.x*256 + threadIdx.x;
    int total = N*32;
    float4 v = make_float4(0.f,0.f,0.f,0.f);
    if (i < total){
      v = ((const float4*)x)[i];
      ushort4 u; u.x=f2bf(v.x); u.y=f2bf(v.y); u.z=f2bf(v.z); u.w=f2bf(v.w);
      ((ushort4*)xb)[i] = u;
    }
    int c = (i & 31) << 2;
    float4 vs0 = *(const float4*)(va + c);
    float4 vs1 = *(const float4*)(va + 128 + c);
    float4 vd0 = *(const float4*)(va + 256 + c);
    float4 vd1 = *(const float4*)(va + 384 + c);
    float s0 = v.x*vs0.x + v.y*vs0.y + v.z*vs0.z + v.w*vs0.w;
    float s1 = v.x*vs1.x + v.y*vs1.y + v.z*vs1.z + v.w*vs1.w;
    float d0 = v.x*vd0.x + v.y*vd0.y + v.z*vd0.z + v.w*vd0.w;
    float d1 = v.x*vd1.x + v.y*vd1.y + v.z*vd1.z + v.w*vd1.w;
    #pragma unroll
    for (int m = 1; m <= 16; m <<= 1){
      s0 += __shfl_xor(s0, m); s1 += __shfl_xor(s1, m);
      d0 += __shfl_xor(d0, m); d1 += __shfl_xor(d1, m);
    }
    if ((i & 31) == 0 && i < total){
      int n = i >> 5;
      *(float2*)(as1 + 2*n) = make_float2(s0, s1);
      *(float2*)(ad1 + 2*n) = make_float2(d0, d1);
    }
  } else {
    for (int i = threadIdx.x; i < NB; i += 256) h[i] = 0;
    __syncthreads();
    int b0 = blockIdx.x - nbConv;                   // 0..63
    for (int e = b0*256 + threadIdx.x; e < E; e += 64*256)
      atomicAdd(&h[dst[e] >> 6], 1);
    __syncthreads();
    for (int i = threadIdx.x; i < NB; i += 256)
      if (h[i]) atomicAdd(&bcount[i], h[i]);
  }
}

// ---------------- bucketed CSR build (bscan/bscatter/bbuild unchanged) ----------------
__global__ __launch_bounds__(1024) void bscan_kernel(const int* __restrict__ bcount,
                                                     int* __restrict__ boff, int NB){
  __shared__ int s[1024];
  int t = threadIdx.x;
  int mine = (t < NB) ? bcount[t] : 0;
  s[t] = mine;
  __syncthreads();
  for (int d = 1; d < 1024; d <<= 1){
    int v = (t >= d) ? s[t-d] : 0;
    __syncthreads();
    s[t] += v;
    __syncthreads();
  }
  if (t < NB) boff[t] = s[t] - mine;
  if (t == NB-1) boff[NB] = s[t];
}

__global__ __launch_bounds__(256) void bscatter_kernel(
    const int* __restrict__ src, const int* __restrict__ dst, int E,
    const int* __restrict__ boff, int* __restrict__ gcur,
    unsigned int* __restrict__ pairs, int NB)
{
  __shared__ int h[1024];
  __shared__ int runbase[1024];
  const int t = threadIdx.x;
  const int e0 = blockIdx.x * 4096;
  for (int i = t; i < NB; i += 256) h[i] = 0;
  __syncthreads();
  int myb[16]; unsigned int myw[16];
  #pragma unroll
  for (int q = 0; q < 16; ++q){
    int e = e0 + q*256 + t;
    int b = -1; unsigned int w = 0;
    if (e < E){
      int d = dst[e];
      b = d >> 6;
      w = ((unsigned int)(d & 63) << 26) | (unsigned int)src[e];
      atomicAdd(&h[b], 1);
    }
    myb[q] = b; myw[q] = w;
  }
  __syncthreads();
  for (int i = t; i < NB; i += 256)
    runbase[i] = h[i] ? atomicAdd(&gcur[i], h[i]) : 0;
  __syncthreads();
  for (int i = t; i < NB; i += 256) h[i] = 0;
  __syncthreads();
  #pragma unroll
  for (int q = 0; q < 16; ++q){
    if (myb[q] >= 0){
      int off = atomicAdd(&h[myb[q]], 1);
      pairs[(size_t)boff[myb[q]] + runbase[myb[q]] + off] = myw[q];
    }
  }
}

__global__ __launch_bounds__(256) void bbuild_kernel(
    const unsigned int* __restrict__ pairs, const int* __restrict__ boff,
    int* __restrict__ rowptr, int* __restrict__ csr, int N)
{
  __shared__ int deg[64], offs[64], cur[64];
  const int b = blockIdx.x;
  const int t = threadIdx.x;
  const int n0 = b << 6;
  const int nNodes = min(64, N - n0);
  const int p0 = boff[b], p1 = boff[b+1];
  const int base = p0 + n0;
  if (t < 64) deg[t] = (t < nNodes) ? 1 : 0;
  __syncthreads();
  for (int i = p0 + t; i < p1; i += 256)
    atomicAdd(&deg[pairs[i] >> 26], 1);
  __syncthreads();
  if (t < 64){
    int x = deg[t];
    #pragma unroll
    for (int d = 1; d < 64; d <<= 1){
      int y = __shfl_up(x, d);
      if (t >= d) x += y;
    }
    offs[t] = x - deg[t];
    cur[t] = 1;
    if (t < nNodes){
      rowptr[n0 + t + 1] = base + x;
      csr[base + x - deg[t]] = n0 + t;
    }
    if (b == 0 && t == 0) rowptr[0] = 0;
  }
  __syncthreads();
  for (int i = p0 + t; i < p1; i += 256){
    unsigned int w = pairs[i];
    int dl = w >> 26;
    int s  = (int)(w & 0x03ffffffu);
    int off = atomicAdd(&cur[dl], 1);
    csr[base + offs[dl] + off] = s;
  }
}

// ---------------- GEMM core: 128-row tile x 128-col, BK=64, bf16 MFMA ----------------
__device__ __forceinline__ void gemm_core(
    const unsigned short* __restrict__ A, int lda,
    const unsigned short* __restrict__ BT, int M, int K, int r0,
    unsigned short* a_s, unsigned short* b_s, f32x4 (&acc)[4][4])
{
  const int tid  = threadIdx.x;
  const int lane = tid & 63, wv = tid >> 6;
  const int mh = (wv & 1)*64, nh = (wv >> 1)*64;
  const int l15 = lane & 15, quad = lane >> 4;
  const int srow = tid >> 3, skc = tid & 7;

  #pragma unroll
  for (int i = 0; i < 4; ++i)
    #pragma unroll
    for (int j = 0; j < 4; ++j)
      #pragma unroll
      for (int r = 0; r < 4; ++r) acc[i][j][r] = 0.f;

  for (int k0 = 0; k0 < K; k0 += 64){
    #pragma unroll
    for (int it = 0; it < 4; ++it){
      int row = it*32 + srow;
      int grow = r0 + row;
      uint4 v = make_uint4(0u,0u,0u,0u);
      if (grow < M) v = *(const uint4*)(A + (size_t)grow*lda + k0 + skc*8);
      *(uint4*)(&a_s[row*72 + skc*8]) = v;
    }
    #pragma unroll
    for (int it = 0; it < 4; ++it){
      int row = it*32 + srow;
      uint4 v = *(const uint4*)(BT + (size_t)row*K + k0 + skc*8);
      *(uint4*)(&b_s[row*72 + skc*8]) = v;
    }
    __syncthreads();
    #pragma unroll
    for (int ks = 0; ks < 64; ks += 32){
      bf16x8 af[4], bfr[4];
      #pragma unroll
      for (int i = 0; i < 4; ++i)
        af[i] = *(const bf16x8*)(&a_s[(mh + i*16 + l15)*72 + ks + quad*8]);
      #pragma unroll
      for (int j = 0; j < 4; ++j)
        bfr[j] = *(const bf16x8*)(&b_s[(nh + j*16 + l15)*72 + ks + quad*8]);
      #pragma unroll
      for (int i = 0; i < 4; ++i)
        #pragma unroll
        for (int j = 0; j < 4; ++j)
          acc[i][j] = __builtin_amdgcn_mfma_f32_16x16x32_bf16(bfr[j], af[i], acc[i][j], 0, 0, 0);
    }
    __syncthreads();
  }
}

// ---------------- conv1 GEMM: both halves (grid.x=2), elu, bf16 out ----------------
__global__ __launch_bounds__(256) void gemm_conv1_kernel(
    const unsigned short* __restrict__ xa, const unsigned short* __restrict__ BT1a,
    const unsigned short* __restrict__ BT1b, unsigned short* __restrict__ out1b,
    int M, const float* __restrict__ b1)
{
  __shared__ unsigned short a_s[128*72];
  __shared__ unsigned short b_s[128*72];
  const int hx = blockIdx.x;
  const unsigned short* A  = xa + hx*128;
  const unsigned short* BT = hx ? BT1b : BT1a;
  unsigned short* C = out1b + hx*128;
  const float* bias = b1 + hx*128;
  const int r0 = blockIdx.y*128;
  f32x4 acc[4][4];
  gemm_core(A, 256, BT, M, 128, r0, a_s, b_s, acc);

  const int lane = threadIdx.x & 63, wv = threadIdx.x >> 6;
  const int mh = (wv & 1)*64, nh = (wv >> 1)*64;
  const int l15 = lane & 15, quad = lane >> 4;
  #pragma unroll
  for (int i = 0; i < 4; ++i){
    int m = r0 + mh + i*16 + l15;
    if (m < M){
      #pragma unroll
      for (int j = 0; j < 4; ++j){
        int n = nh + j*16 + quad*4;
        float4 bb = *(const float4*)(bias + n);
        ushort4 u;
        u.x = f2bf(elu_f(acc[i][j][0] + bb.x));
        u.y = f2bf(elu_f(acc[i][j][1] + bb.y));
        u.z = f2bf(elu_f(acc[i][j][2] + bb.z));
        u.w = f2bf(elu_f(acc[i][j][3] + bb.w));
        *(ushort4*)(C + (size_t)m*256 + n) = u;
      }
    }
  }
}

// ---------------- conv2 GEMM: h2b bf16 out + fused asad2 ----------------
__global__ __launch_bounds__(256) void gemm_conv2_kernel(
    const unsigned short* __restrict__ out1b, const unsigned short* __restrict__ BT2,
    unsigned short* __restrict__ h2b, int M,
    const float* __restrict__ a2s, const float* __restrict__ a2d,
    float* __restrict__ as2, float* __restrict__ ad2)
{
  __shared__ unsigned short a_s[128*72];
  __shared__ unsigned short b_s[128*72];
  __shared__ float part_s[128][2];
  __shared__ float part_d[128][2];
  const int r0 = blockIdx.y*128;
  f32x4 acc[4][4];
  gemm_core(out1b, 256, BT2, M, 256, r0, a_s, b_s, acc);

  const int tid = threadIdx.x;
  const int lane = tid & 63, wv = tid >> 6;
  const int mh = (wv & 1)*64, nh = (wv >> 1)*64;
  const int l15 = lane & 15, quad = lane >> 4;
  #pragma unroll
  for (int i = 0; i < 4; ++i){
    int m = r0 + mh + i*16 + l15;
    float ps = 0.f, pd = 0.f;
    #pragma unroll
    for (int j = 0; j < 4; ++j){
      int n = nh + j*16 + quad*4;
      float4 wsv = *(const float4*)(a2s + n);
      float4 wdv = *(const float4*)(a2d + n);
      float v0 = acc[i][j][0], v1 = acc[i][j][1], v2 = acc[i][j][2], v3 = acc[i][j][3];
      ps += v0*wsv.x + v1*wsv.y + v2*wsv.z + v3*wsv.w;
      pd += v0*wdv.x + v1*wdv.y + v2*wdv.z + v3*wdv.w;
      if (m < M){
        ushort4 u;
        u.x = f2bf(v0); u.y = f2bf(v1); u.z = f2bf(v2); u.w = f2bf(v3);
        *(ushort4*)(h2b + (size_t)m*128 + n) = u;
      }
    }
    ps += __shfl_xor(ps, 16); ps += __shfl_xor(ps, 32);
    pd += __shfl_xor(pd, 16); pd += __shfl_xor(pd, 32);
    if (quad == 0){
      part_s[mh + i*16 + l15][wv >> 1] = ps;
      part_d[mh + i*16 + l15][wv >> 1] = pd;
    }
  }
  __syncthreads();
  if (tid < 128){
    int gm = r0 + tid;
    if (gm < M){
      as2[gm] = part_s[tid][0] + part_s[tid][1];
      ad2[gm] = part_d[tid][0] + part_d[tid][1];
    }
  }
}

// ---------------- MLP GEMM: relu(gb@Wm1+bm1) then fused @Wm2+bm2,relu -> d_out ----------------
__global__ __launch_bounds__(256) void gemm_mlp_kernel(
    const unsigned short* __restrict__ gb, const unsigned short* __restrict__ BT3,
    int M, const float* __restrict__ bm1, const float* __restrict__ Wm2,
    const float* __restrict__ bm2, float* __restrict__ out)
{
  __shared__ unsigned short a_s[128*72];
  __shared__ unsigned short b_s[128*72];
  __shared__ float wm2_s[128*8];
  __shared__ float part[128][2][8];
  const int tid = threadIdx.x;
  {
    int i4 = tid*4;                 // 1024 floats, 4 per thread
    *(float4*)(&wm2_s[i4]) = *(const float4*)(Wm2 + i4);
  }
  const int r0 = blockIdx.y*128;
  f32x4 acc[4][4];
  gemm_core(gb, 128, BT3, M, 128, r0, a_s, b_s, acc);

  const int lane = tid & 63, wv = tid >> 6;
  const int mh = (wv & 1)*64, nh = (wv >> 1)*64;
  const int l15 = lane & 15, quad = lane >> 4;
  #pragma unroll
  for (int i = 0; i < 4; ++i){
    float po[8];
    #pragma unroll
    for (int o = 0; o < 8; ++o) po[o] = 0.f;
    #pragma unroll
    for (int j = 0; j < 4; ++j){
      int n = nh + j*16 + quad*4;
      float4 bb = *(const float4*)(bm1 + n);
      #pragma unroll
      for (int r = 0; r < 4; ++r){
        float hcol = fmaxf(acc[i][j][r] + ((const float*)&bb)[r], 0.f);
        const float* wr = &wm2_s[(n + r)*8];
        #pragma unroll
        for (int o = 0; o < 8; ++o) po[o] += hcol*wr[o];
      }
    }
    #pragma unroll
    for (int o = 0; o < 8; ++o){
      po[o] += __shfl_xor(po[o], 16);
      po[o] += __shfl_xor(po[o], 32);
    }
    if (quad == 0){
      #pragma unroll
      for (int o = 0; o < 8; ++o) part[mh + i*16 + l15][wv >> 1][o] = po[o];
    }
  }
  __syncthreads();
  if (tid < 128){
    int gm = r0 + tid;
    if (gm < M){
      float4 o0, o1;
      o0.x = fmaxf(part[tid][0][0] + part[tid][1][0] + bm2[0], 0.f);
      o0.y = fmaxf(part[tid][0][1] + part[tid][1][1] + bm2[1], 0.f);
      o0.z = fmaxf(part[tid][0][2] + part[tid][1][2] + bm2[2], 0.f);
      o0.w = fmaxf(part[tid][0][3] + part[tid][1][3] + bm2[3], 0.f);
      o1.x = fmaxf(part[tid][0][4] + part[tid][1][4] + bm2[4], 0.f);
      o1.y = fmaxf(part[tid][0][5] + part[tid][1][5] + bm2[5], 0.f);
      o1.z = fmaxf(part[tid][0][6] + part[tid][1][6] + bm2[6], 0.f);
      o1.w = fmaxf(part[tid][0][7] + part[tid][1][7] + bm2[7], 0.f);
      *(float4*)(out + (size_t)gm*8)     = o0;
      *(float4*)(out + (size_t)gm*8 + 4) = o1;
    }
  }
}

// ---------------- agg1x: aggregate x rows with 2-head alphas (unchanged) ----------------
__global__ __launch_bounds__(256) void agg1x_kernel(
    const unsigned short* __restrict__ xb, const float* __restrict__ as_,
    const float* __restrict__ ad_, const int* __restrict__ rowptr, const int* __restrict__ csr,
    unsigned short* __restrict__ xa, int N)
{
  const int wv = threadIdx.x >> 6, lane = threadIdx.x & 63;
  const int ql = lane & 15;
  const int n = blockIdx.x*16 + wv*4 + (lane >> 4);
  const bool valid = n < N;
  int start = 0, end = 0;
  float2 adv = make_float2(0.f, 0.f);
  if (valid){ start = rowptr[n]; end = rowptr[n+1]; adv = *(const float2*)(ad_ + 2*n); }

  int jl = start + ql;
  bool have = valid && (jl < end);
  int s_l = 0;
  float p0 = 0.f, p1 = 0.f;
  if (have){
    s_l = csr[jl];
    float2 av = *(const float2*)(as_ + 2*s_l);
    p0 = __expf(lrelu(av.x + adv.x));
    p1 = __expf(lrelu(av.y + adv.y));
  }
  float l0 = p0, l1 = p1;
  for (int j = jl + 16; j < end; j += 16){
    int s = csr[j];
    float2 av = *(const float2*)(as_ + 2*s);
    l0 += __expf(lrelu(av.x + adv.x));
    l1 += __expf(lrelu(av.y + adv.y));
  }
  #pragma unroll
  for (int msk = 1; msk <= 8; msk <<= 1){
    l0 += __shfl_xor(l0, msk);
    l1 += __shfl_xor(l1, msk);
  }
  float inv0 = 1.f / fmaxf(l0, 1e-16f);
  float inv1 = 1.f / fmaxf(l1, 1e-16f);
  float a0_l = p0 * inv0;
  float a1_l = p1 * inv1;

  float acc0[8], acc1[8];
  #pragma unroll
  for (int i = 0; i < 8; ++i){ acc0[i] = 0.f; acc1[i] = 0.f; }
  const int c = ql << 3;
  const unsigned short* hp = xb + c;

  int cnt = valid ? min(16, end - start) : 0;
  for (int t = 0; t < cnt; ++t){
    int   sA  = __shfl(s_l, t, 16);
    float a0A = __shfl(a0_l, t, 16);
    float a1A = __shfl(a1_l, t, 16);
    uint4 u = *(const uint4*)(hp + (sA << 7));
    float f0 = bflo(u.x), f1 = bfhi(u.x), f2v = bflo(u.y), f3 = bfhi(u.y);
    float f4 = bflo(u.z), f5 = bfhi(u.z), f6 = bflo(u.w), f7 = bfhi(u.w);
    acc0[0] += a0A*f0; acc0[1] += a0A*f1; acc0[2] += a0A*f2v; acc0[3] += a0A*f3;
    acc0[4] += a0A*f4; acc0[5] += a0A*f5; acc0[6] += a0A*f6;  acc0[7] += a0A*f7;
    acc1[0] += a1A*f0; acc1[1] += a1A*f1; acc1[2] += a1A*f2v; acc1[3] += a1A*f3;
    acc1[4] += a1A*f4; acc1[5] += a1A*f5; acc1[6] += a1A*f6;  acc1[7] += a1A*f7;
  }
  for (int jb = start + 16; jb < end; jb += 16){
    int jl2 = jb + ql;
    int s2 = 0; float a0_2 = 0.f, a1_2 = 0.f;
    if (jl2 < end){
      s2 = csr[jl2];
      float2 av = *(const float2*)(as_ + 2*s2);
      a0_2 = __expf(lrelu(av.x + adv.x)) * inv0;
      a1_2 = __expf(lrelu(av.y + adv.y)) * inv1;
    }
    int cnt2 = min(16, end - jb);
    for (int t2 = 0; t2 < cnt2; ++t2){
      int   sA  = __shfl(s2, t2, 16);
      float a0A = __shfl(a0_2, t2, 16);
      float a1A = __shfl(a1_2, t2, 16);
      uint4 u = *(const uint4*)(hp + (sA << 7));
      float f0 = bflo(u.x), f1 = bfhi(u.x), f2v = bflo(u.y), f3 = bfhi(u.y);
      float f4 = bflo(u.z), f5 = bfhi(u.z), f6 = bflo(u.w), f7 = bfhi(u.w);
      acc0[0] += a0A*f0; acc0[1] += a0A*f1; acc0[2] += a0A*f2v; acc0[3] += a0A*f3;
      acc0[4] += a0A*f4; acc0[5] += a0A*f5; acc0[6] += a0A*f6;  acc0[7] += a0A*f7;
      acc1[0] += a1A*f0; acc1[1] += a1A*f1; acc1[2] += a1A*f2v; acc1[3] += a1A*f3;
      acc1[4] += a1A*f4; acc1[5] += a1A*f5; acc1[6] += a1A*f6;  acc1[7] += a1A*f7;
    }
  }

  if (valid){
    uint4 u0, u1;
    u0.x = packbf(acc0[0], acc0[1]); u0.y = packbf(acc0[2], acc0[3]);
    u0.z = packbf(acc0[4], acc0[5]); u0.w = packbf(acc0[6], acc0[7]);
    u1.x = packbf(acc1[0], acc1[1]); u1.y = packbf(acc1[2], acc1[3]);
    u1.z = packbf(acc1[4], acc1[5]); u1.w = packbf(acc1[6], acc1[7]);
    *(uint4*)(xa + (size_t)n*256 + c)       = u0;
    *(uint4*)(xa + (size_t)n*256 + 128 + c) = u1;
  }
}

// ---------------- agg2: 4 nodes/wave, 16 lanes/node (unchanged) ----------------
__global__ __launch_bounds__(256) void agg2_kernel(
    const unsigned short* __restrict__ h2b, const float* __restrict__ as_,
    const float* __restrict__ ad_, const int* __restrict__ rowptr, const int* __restrict__ csr,
    const float* __restrict__ b2, unsigned short* __restrict__ outb, int N)
{
  const int wv = threadIdx.x >> 6, lane = threadIdx.x & 63;
  const int ql = lane & 15;
  const int n = blockIdx.x*16 + wv*4 + (lane >> 4);
  const bool valid = n < N;
  int start = 0, end = 0;
  float adn = 0.f;
  if (valid){ start = rowptr[n]; end = rowptr[n+1]; adn = ad_[n]; }

  int jl = start + ql;
  bool have = valid && (jl < end);
  int s_l = 0;
  float p_l = 0.f;
  if (have){
    s_l = csr[jl];
    p_l = __expf(lrelu(as_[s_l] + adn));
  }
  float l = p_l;
  for (int j = jl + 16; j < end; j += 16)
    l += __expf(lrelu(as_[csr[j]] + adn));
  #pragma unroll
  for (int msk = 1; msk <= 8; msk <<= 1) l += __shfl_xor(l, msk);
  float inv = 1.f / fmaxf(l, 1e-16f);
  float a_l = p_l * inv;

  float acc[8];
  #pragma unroll
  for (int i = 0; i < 8; ++i) acc[i] = 0.f;
  const int c = ql << 3;
  const unsigned short* hp = h2b + c;

  int cnt = valid ? min(16, end - start) : 0;
  int t = 0;
  for (; t + 1 < cnt; t += 2){
    int   sA = __shfl(s_l, t, 16),  sB = __shfl(s_l, t+1, 16);
    float aA = __shfl(a_l, t, 16),  aB = __shfl(a_l, t+1, 16);
    uint4 uA = *(const uint4*)(hp + (sA << 7));
    uint4 uB = *(const uint4*)(hp + (sB << 7));
    acc[0] += aA*bflo(uA.x) + aB*bflo(uB.x);
    acc[1] += aA*bfhi(uA.x) + aB*bfhi(uB.x);
    acc[2] += aA*bflo(uA.y) + aB*bflo(uB.y);
    acc[3] += aA*bfhi(uA.y) + aB*bfhi(uB.y);
    acc[4] += aA*bflo(uA.z) + aB*bflo(uB.z);
    acc[5] += aA*bfhi(uA.z) + aB*bfhi(uB.z);
    acc[6] += aA*bflo(uA.w) + aB*bflo(uB.w);
    acc[7] += aA*bfhi(uA.w) + aB*bfhi(uB.w);
  }
  if (t < cnt){
    int   sA = __shfl(s_l, t, 16);
    float aA = __shfl(a_l, t, 16);
    uint4 uA = *(const uint4*)(hp + (sA << 7));
    acc[0] += aA*bflo(uA.x); acc[1] += aA*bfhi(uA.x);
    acc[2] += aA*bflo(uA.y); acc[3] += aA*bfhi(uA.y);
    acc[4] += aA*bflo(uA.z); acc[5] += aA*bfhi(uA.z);
    acc[6] += aA*bflo(uA.w); acc[7] += aA*bfhi(uA.w);
  }
  for (int jb = start + 16; jb < end; jb += 16){
    int jl2 = jb + ql;
    int s2 = 0; float a2 = 0.f;
    if (jl2 < end){
      s2 = csr[jl2];
      a2 = __expf(lrelu(as_[s2] + adn)) * inv;
    }
    int cnt2 = min(16, end - jb);
    for (int t2 = 0; t2 < cnt2; ++t2){
      int   sA = __shfl(s2, t2, 16);
      float aA = __shfl(a2, t2, 16);
      uint4 uA = *(const uint4*)(hp + (sA << 7));
      acc[0] += aA*bflo(uA.x); acc[1] += aA*bfhi(uA.x);
      acc[2] += aA*bflo(uA.y); acc[3] += aA*bfhi(uA.y);
      acc[4] += aA*bflo(uA.z); acc[5] += aA*bfhi(uA.z);
      acc[6] += aA*bflo(uA.w); acc[7] += aA*bfhi(uA.w);
    }
  }

  if (valid){
    float4 bb0 = *(const float4*)(b2 + c);
    float4 bb1 = *(const float4*)(b2 + c + 4);
    float o[8];
    o[0]=elu_f(acc[0]+bb0.x); o[1]=elu_f(acc[1]+bb0.y);
    o[2]=elu_f(acc[2]+bb0.z); o[3]=elu_f(acc[3]+bb0.w);
    o[4]=elu_f(acc[4]+bb1.x); o[5]=elu_f(acc[5]+bb1.y);
    o[6]=elu_f(acc[6]+bb1.z); o[7]=elu_f(acc[7]+bb1.w);
    uint4 up;
    up.x = packbf(o[0], o[1]); up.y = packbf(o[2], o[3]);
    up.z = packbf(o[4], o[5]); up.w = packbf(o[6], o[7]);
    *(uint4*)(outb + (size_t)n*128 + c) = up;
  }
}

extern "C" void kernel_launch(void* const* d_in, const int* in_sizes, int n_in,
                              void* d_out, int out_size, void* d_ws, size_t ws_size,
                              hipStream_t stream)
{
  (void)n_in; (void)out_size; (void)ws_size;
  const float* x   = (const float*)d_in[0];
  const int*   ei  = (const int*)d_in[1];
  const float* W1  = (const float*)d_in[2];
  const float* a1s = (const float*)d_in[3];
  const float* a1d = (const float*)d_in[4];
  const float* b1  = (const float*)d_in[5];
  const float* W2  = (const float*)d_in[6];
  const float* a2s = (const float*)d_in[7];
  const float* a2d = (const float*)d_in[8];
  const float* b2  = (const float*)d_in[9];
  const float* Wm1 = (const float*)d_in[10];
  const float* bm1 = (const float*)d_in[11];
  const float* Wm2 = (const float*)d_in[12];
  const float* bm2 = (const float*)d_in[13];
  float* out = (float*)d_out;

  const int N = in_sizes[0] / 128;
  const int E = in_sizes[1] / 2;
  const int NB = (N + 63) >> 6;
  const int* srcp = ei;
  const int* dstp = ei + E;

  char* ws = (char*)d_ws;
  unsigned short* xb    = (unsigned short*)ws;                       // [N,128] bf16 -> gb later
  unsigned short* xa    = (unsigned short*)(ws + (size_t)N*256);     // [N,256] bf16
  unsigned short* out1b = (unsigned short*)(ws + (size_t)N*768);     // [N,256] bf16
  unsigned short* h2b   = (unsigned short*)(ws + (size_t)N*1280);    // [N,128] bf16
  char* tail = ws + (size_t)N*1536;
  unsigned short* BT1a = (unsigned short*)tail;
  unsigned short* BT1b = BT1a + 128*128;
  unsigned short* BT2  = BT1b + 128*128;
  unsigned short* BT3  = BT2 + 128*256;
  float* va   = (float*)(BT3 + 128*128);
  float* as1  = va + 512;
  float* ad1  = as1 + (size_t)2*N;
  float* as2  = ad1 + (size_t)2*N;
  float* ad2  = as2 + N;
  int* bcount = (int*)(ad2 + N);
  int* boff   = bcount + 1024;
  int* gcur   = boff + 1032;
  int* rowptr = gcur + 1024;
  int* csr    = rowptr + N + 1;
  unsigned int* pairs = (unsigned int*)(csr + E + N);

  unsigned short* gb = xb;            // xb dead after agg1x

  const int nbConv = (N*32 + 255)/256;
  const int prepTotal = 128*128 + 128*256 + 128*128 + 512 + 2048;

  // 1: prep (va + weight transposes + zero bucket arrays)
  prep_kernel<<<(prepTotal + 255)/256, 256, 0, stream>>>(
      W1, BT1a, BT1b, W2, BT2, Wm1, BT3, a1s, a1d, va, bcount, gcur, NB);
  // 2: x convert + conv1 alpha dots + edge histogram
  f2bf_hist_kernel<<<nbConv + 64, 256, 0, stream>>>(x, xb, N, va, as1, ad1,
                                                    dstp, E, bcount, NB, nbConv);
  // 3-5: bucketed CSR
  bscan_kernel<<<1, 1024, 0, stream>>>(bcount, boff, NB);
  bscatter_kernel<<<(E + 4095)/4096, 256, 0, stream>>>(srcp, dstp, E, boff, gcur, pairs, NB);
  bbuild_kernel<<<NB, 256, 0, stream>>>(pairs, boff, rowptr, csr, N);

  const int gy   = (N + 127) / 128;
  const int nb16 = (N + 15) / 16;

  // 6: conv1 aggregation (gathers x)
  agg1x_kernel<<<nb16, 256, 0, stream>>>(xb, as1, ad1, rowptr, csr, xa, N);
  // 7: conv1 projection, both heads
  gemm_conv1_kernel<<<dim3(2, gy), 256, 0, stream>>>(xa, BT1a, BT1b, out1b, N, b1);
  // 8: conv2 projection + fused asad2
  gemm_conv2_kernel<<<dim3(1, gy), 256, 0, stream>>>(out1b, BT2, h2b, N, a2s, a2d, as2, ad2);
  // 9: conv2 aggregation
  agg2_kernel<<<nb16, 256, 0, stream>>>(h2b, as2, ad2, rowptr, csr, b2, gb, N);
  // 10: MLP (gemm + fused second layer) -> d_out
  gemm_mlp_kernel<<<dim3(1, gy), 256, 0, stream>>>(gb, BT3, N, bm1, Wm2, bm2, out);
}